// Round 5
// baseline (288.764 us; speedup 1.0000x reference)
//
#include <hip/hip_runtime.h>
#include <hip/hip_bf16.h>
#include <stdint.h>

// Problem constants (reference: B=2, D=128, H=64, W=64)
#define BN 2
#define DN 128
#define MN 4096                 // H*W pixels per image
#define TOTAL_INV (1.0f / 33554432.0f)   // 1 / (B*M*N)
#define NPART 8192              // 2048 blocks x 4 waves

typedef __attribute__((ext_vector_type(8))) short short8;   // 8 bf16 = 4 VGPRs
typedef __attribute__((ext_vector_type(4))) float f32x4;

__device__ static inline unsigned short f2bf(float x) {
  unsigned int u = __float_as_uint(x);
  u += 0x7fffu + ((u >> 16) & 1u);      // RNE f32 -> bf16
  return (unsigned short)(u >> 16);
}

// [B, D, M] f32 -> [B, M, D] bf16
__global__ __launch_bounds__(256) void transpose_cvt(
    const float* __restrict__ s0, const float* __restrict__ s1,
    unsigned short* __restrict__ o0, unsigned short* __restrict__ o1) {
  __shared__ float tile[64][65];
  const int tx = threadIdx.x & 63;
  const int ty = threadIdx.x >> 6;
  const int m0 = blockIdx.x * 64;
  const int d0 = blockIdx.y * 64;
  const int b  = blockIdx.z & 1;
  const float* src = (blockIdx.z >> 1) ? s1 : s0;
  unsigned short* dst = (blockIdx.z >> 1) ? o1 : o0;
  src += (size_t)b * DN * MN;
  dst += (size_t)b * MN * DN;
#pragma unroll
  for (int i = 0; i < 16; ++i) {
    int dr = i * 4 + ty;
    tile[dr][tx] = src[(size_t)(d0 + dr) * MN + m0 + tx];
  }
  __syncthreads();
#pragma unroll
  for (int i = 0; i < 16; ++i) {
    int mr = i * 4 + ty;
    dst[(size_t)(m0 + mr) * DN + d0 + tx] = f2bf(tile[tx][mr]);
  }
}

// Fused bf16 MFMA GEMM (C = A * B^T) + hinge loss + partial sums.
// grid (N/128, M/128, B), block 256 = 4 waves in 2x2; each wave owns an
// independent 64x64 tile. No LDS, no barriers, no atomics. Epilogue uses a
// UNIFORM branch on mask dtype (no speculative/OOB loads) and coalesced
// dword mask reads + in-quad shuffles for the u8 path.
__global__ __launch_bounds__(256, 3) void gemm_loss(
    const unsigned short* __restrict__ A, const unsigned short* __restrict__ Bm,
    const void* __restrict__ maskp, float* __restrict__ part) {
  const int tid  = threadIdx.x;
  const int lane = tid & 63;
  const int wave = tid >> 6;
  const int wm = wave >> 1, wn = wave & 1;
  const int quad = lane >> 4;
  const int l16  = lane & 15;
  const int bz = blockIdx.z;
  const int gm = blockIdx.y * 128 + wm * 64;   // wave-tile origin (rows of A)
  const int gn = blockIdx.x * 128 + wn * 64;   // wave-tile origin (rows of B)

  // mask dtype sniff -> SGPR-uniform bool (ballot lives in scalar regs):
  // i32 {0,1} storage has zero high bytes in every word; u8 doesn't.
  unsigned sw = ((const unsigned int*)maskp)[lane];
  const bool mask_u8 = (__ballot((sw & 0xFFFFFF00u) != 0u) != 0ull);

  const unsigned short* Ab = A  + (size_t)bz * MN * DN + (size_t)gm * DN;
  const unsigned short* Bb = Bm + (size_t)bz * MN * DN + (size_t)gn * DN;

  f32x4 acc[4][4];
#pragma unroll
  for (int i = 0; i < 4; ++i)
#pragma unroll
    for (int j = 0; j < 4; ++j) acc[i][j] = (f32x4){0.f, 0.f, 0.f, 0.f};

  // K=128 as 4 chunks of 32, 2-deep software pipeline (double-buffered frags)
  short8 af[2][4], bf[2][4];
#pragma unroll
  for (int mi = 0; mi < 4; ++mi)
    af[0][mi] = *(const short8*)(Ab + (size_t)(mi * 16 + l16) * DN + quad * 8);
#pragma unroll
  for (int ni = 0; ni < 4; ++ni)
    bf[0][ni] = *(const short8*)(Bb + (size_t)(ni * 16 + l16) * DN + quad * 8);

#pragma unroll
  for (int kt = 0; kt < 4; ++kt) {
    const int cur = kt & 1, nxt = cur ^ 1;
    if (kt < 3) {
      const int k0 = (kt + 1) * 32 + quad * 8;
#pragma unroll
      for (int mi = 0; mi < 4; ++mi)
        af[nxt][mi] = *(const short8*)(Ab + (size_t)(mi * 16 + l16) * DN + k0);
#pragma unroll
      for (int ni = 0; ni < 4; ++ni)
        bf[nxt][ni] = *(const short8*)(Bb + (size_t)(ni * 16 + l16) * DN + k0);
    }
#pragma unroll
    for (int mi = 0; mi < 4; ++mi)
#pragma unroll
      for (int ni = 0; ni < 4; ++ni)
        acc[mi][ni] = __builtin_amdgcn_mfma_f32_16x16x32_bf16(
            af[cur][mi], bf[cur][ni], acc[mi][ni], 0, 0, 0);
  }

  // ---- epilogue: hinge loss under mask. C/D: col=l16 (n), row=quad*4+r (m).
  const size_t mbase = ((size_t)bz * MN + (size_t)gm) * MN + (size_t)gn;
  float lsum = 0.0f;

  if (mask_u8) {
    // u8 mask: per (mi,r) one coalesced dword row-segment load per lane
    // (4 rows x 64B = 4 full segments / wave), then in-quad shuffles.
    const unsigned char* mrow = (const unsigned char*)maskp + mbase;
    const int srcbase = quad * 16 + (l16 >> 2);
    const int shift = 8 * (l16 & 3);
#pragma unroll
    for (int mi = 0; mi < 4; ++mi) {
#pragma unroll
      for (int r = 0; r < 4; ++r) {
        int m = mi * 16 + quad * 4 + r;
        unsigned w = *(const unsigned*)(mrow + (size_t)m * MN + 4 * l16);
#pragma unroll
        for (int ni = 0; ni < 4; ++ni) {
          unsigned ws = __shfl(w, srcbase + 4 * ni, 64);
          int msk = (ws >> shift) & 0xff;
          float dot = acc[mi][ni][r];
          float pos = fmaxf(0.0f, 1.0f - dot) * 250.0f;
          float neg = fmaxf(0.0f, dot - 0.2f);
          lsum += msk ? pos : neg;
        }
      }
    }
  } else {
    // i32 mask: direct dword loads are already wave-coalesced (4 x 64B segs)
    const int* mi32 = (const int*)maskp;
#pragma unroll
    for (int mi = 0; mi < 4; ++mi) {
#pragma unroll
      for (int ni = 0; ni < 4; ++ni) {
        f32x4 v = acc[mi][ni];
#pragma unroll
        for (int r = 0; r < 4; ++r) {
          int m = mi * 16 + quad * 4 + r;
          int n = ni * 16 + l16;
          int msk = mi32[mbase + (size_t)m * MN + n];
          float dot = v[r];
          float pos = fmaxf(0.0f, 1.0f - dot) * 250.0f;
          float neg = fmaxf(0.0f, dot - 0.2f);
          lsum += msk ? pos : neg;
        }
      }
    }
  }

#pragma unroll
  for (int off = 32; off > 0; off >>= 1) lsum += __shfl_xor(lsum, off);
  if (lane == 0) {
    size_t slot =
        (((size_t)bz * gridDim.y + blockIdx.y) * gridDim.x + blockIdx.x) * 4 + wave;
    part[slot] = lsum;                      // contention-free store
  }
}

// Sum 8192 partials -> out[0]. One block; overwrites out (no pre-zero needed).
__global__ __launch_bounds__(1024) void reduce_partials(
    const float* __restrict__ part, float* __restrict__ out) {
  float s = 0.0f;
#pragma unroll
  for (int i = 0; i < NPART / 1024; ++i) s += part[threadIdx.x + i * 1024];
#pragma unroll
  for (int off = 32; off > 0; off >>= 1) s += __shfl_xor(s, off);
  __shared__ float red[16];
  if ((threadIdx.x & 63) == 0) red[threadIdx.x >> 6] = s;
  __syncthreads();
  if (threadIdx.x == 0) {
    float t = 0.0f;
#pragma unroll
    for (int i = 0; i < 16; ++i) t += red[i];
    *out = t * TOTAL_INV;
  }
}

extern "C" void kernel_launch(void* const* d_in, const int* in_sizes, int n_in,
                              void* d_out, int out_size, void* d_ws, size_t ws_size,
                              hipStream_t stream) {
  const float* d0 = (const float*)d_in[0];
  const float* d1 = (const float*)d_in[1];
  const void* mask = d_in[2];
  float* out = (float*)d_out;

  unsigned short* Aw = (unsigned short*)d_ws;            // [B, M, D] bf16, 2 MB
  unsigned short* Bw = Aw + (size_t)BN * MN * DN;        // [B, M, D] bf16, 2 MB
  float* part = (float*)(Bw + (size_t)BN * MN * DN);     // 8192 f32, 32 KB

  dim3 g1(MN / 64, DN / 64, BN * 2), b1(256);
  transpose_cvt<<<g1, b1, 0, stream>>>(d0, d1, Aw, Bw);

  dim3 g2(MN / 128, MN / 128, BN), b2(256);
  gemm_loss<<<g2, b2, 0, stream>>>(Aw, Bw, mask, part);

  reduce_partials<<<1, 1024, 0, stream>>>(part, out);
}

// Round 6
// 209.250 us; speedup vs baseline: 1.3800x; 1.3800x over previous
//
#include <hip/hip_runtime.h>
#include <hip/hip_bf16.h>
#include <stdint.h>

// Problem constants (reference: B=2, D=128, H=64, W=64)
#define BN 2
#define DN 128
#define MN 4096                 // H*W pixels per image
#define TOTAL_INV (1.0f / 33554432.0f)   // 1 / (B*M*N)
#define NPART 8192              // 2048 blocks x 4 waves

typedef __attribute__((ext_vector_type(8))) short short8;   // 8 bf16 = 4 VGPRs
typedef __attribute__((ext_vector_type(4))) float f32x4;

__device__ static inline unsigned short f2bf(float x) {
  unsigned int u = __float_as_uint(x);
  u += 0x7fffu + ((u >> 16) & 1u);      // RNE f32 -> bf16
  return (unsigned short)(u >> 16);
}

__device__ static inline void async16(const void* g, void* l) {
  // 16B global -> LDS direct copy; LDS dest = wave-uniform base + lane*16
  __builtin_amdgcn_global_load_lds(
      (const __attribute__((address_space(1))) void*)g,
      (__attribute__((address_space(3))) void*)l, 16, 0, 0);
}

// [B, D, M] f32 -> [B, M, D] bf16
__global__ __launch_bounds__(256) void transpose_cvt(
    const float* __restrict__ s0, const float* __restrict__ s1,
    unsigned short* __restrict__ o0, unsigned short* __restrict__ o1) {
  __shared__ float tile[64][65];
  const int tx = threadIdx.x & 63;
  const int ty = threadIdx.x >> 6;
  const int m0 = blockIdx.x * 64;
  const int d0 = blockIdx.y * 64;
  const int b  = blockIdx.z & 1;
  const float* src = (blockIdx.z >> 1) ? s1 : s0;
  unsigned short* dst = (blockIdx.z >> 1) ? o1 : o0;
  src += (size_t)b * DN * MN;
  dst += (size_t)b * MN * DN;
#pragma unroll
  for (int i = 0; i < 16; ++i) {
    int dr = i * 4 + ty;
    tile[dr][tx] = src[(size_t)(d0 + dr) * MN + m0 + tx];
  }
  __syncthreads();
#pragma unroll
  for (int i = 0; i < 16; ++i) {
    int mr = i * 4 + ty;
    dst[(size_t)(m0 + mr) * DN + d0 + tx] = f2bf(tile[tx][mr]);
  }
}

// Fused bf16 MFMA GEMM (C = A * B^T) + hinge loss + partial sums.
// R1-core revival: LDS-shared A/B staging via global_load_lds (16 KB LDS),
// grid (N/128, M/128, B), block 256 = 4 waves 2x2, each wave 64x64 out.
// Epilogue: direct per-element mask loads (R1/R4 style — measured fastest).
// NO atomics: one partial store per wave, reduced by reduce_partials.
__global__ __launch_bounds__(256) void gemm_loss(
    const unsigned short* __restrict__ A, const unsigned short* __restrict__ Bm,
    const void* __restrict__ maskp, float* __restrict__ part) {
  __shared__ __align__(16) unsigned short As[128 * 32];   // [m][k] k-contig, 8 KB
  __shared__ __align__(16) unsigned short Bs[128 * 32];   // [n][k] k-contig, 8 KB

  const int tid  = threadIdx.x;
  const int lane = tid & 63;
  const int wave = tid >> 6;
  const int wm = wave >> 1, wn = wave & 1;
  const int quad = lane >> 4;
  const int l16  = lane & 15;
  const int bn = blockIdx.x, bm = blockIdx.y, bz = blockIdx.z;

  // mask dtype sniff -> wave-uniform bool, no barrier:
  // i32 {0,1} storage has zero high bytes in every word; u8 doesn't.
  unsigned sw = ((const unsigned int*)maskp)[lane];
  const bool mask_u8 = (__ballot((sw & 0xFFFFFF00u) != 0u) != 0ull);

  const unsigned short* Ab = A  + (size_t)bz * MN * DN + (size_t)(bm * 128) * DN;
  const unsigned short* Bb = Bm + (size_t)bz * MN * DN + (size_t)(bn * 128) * DN;

  f32x4 acc[4][4];
#pragma unroll
  for (int i = 0; i < 4; ++i)
#pragma unroll
    for (int j = 0; j < 4; ++j) acc[i][j] = (f32x4){0.f, 0.f, 0.f, 0.f};

#pragma unroll
  for (int kt = 0; kt < 4; ++kt) {
    const int k0 = kt * 32;
    // stage 128x32 bf16 tiles: 512 x 16B chunks, 2 per thread
#pragma unroll
    for (int p = 0; p < 2; ++p) {
      int c = tid + p * 256;
      int row = c >> 2;      // 4 chunks (64B) per row
      int cq  = c & 3;
      async16(Ab + (size_t)row * DN + k0 + cq * 8, As + (size_t)c * 8);
      async16(Bb + (size_t)row * DN + k0 + cq * 8, Bs + (size_t)c * 8);
    }
    __syncthreads();                        // vmcnt(0) drain

    short8 af[4], bf[4];
#pragma unroll
    for (int mi = 0; mi < 4; ++mi)          // ds_read_b128: A[m=l16][k=quad*8..]
      af[mi] = *(const short8*)(As + (wm * 64 + mi * 16 + l16) * 32 + quad * 8);
#pragma unroll
    for (int ni = 0; ni < 4; ++ni)
      bf[ni] = *(const short8*)(Bs + (wn * 64 + ni * 16 + l16) * 32 + quad * 8);
#pragma unroll
    for (int mi = 0; mi < 4; ++mi)
#pragma unroll
      for (int ni = 0; ni < 4; ++ni)
        acc[mi][ni] = __builtin_amdgcn_mfma_f32_16x16x32_bf16(
            af[mi], bf[ni], acc[mi][ni], 0, 0, 0);
    if (kt != 3) __syncthreads();           // last kt: no trailing barrier
  }

  // ---- epilogue: hinge loss under mask (direct global loads), wave reduce,
  // ONE contention-free store per wave. C/D: col=l16 (n), row=quad*4+r (m).
  const size_t mbase = ((size_t)bz * MN + (size_t)(bm * 128 + wm * 64)) * MN
                       + (size_t)(bn * 128 + wn * 64);
  const int* mi32 = (const int*)maskp;
  const unsigned char* mu8 = (const unsigned char*)maskp;
  float lsum = 0.0f;
#pragma unroll
  for (int mi = 0; mi < 4; ++mi) {
#pragma unroll
    for (int ni = 0; ni < 4; ++ni) {
      f32x4 v = acc[mi][ni];
#pragma unroll
      for (int r = 0; r < 4; ++r) {
        int m = mi * 16 + quad * 4 + r;
        int n = ni * 16 + l16;
        size_t idx = mbase + (size_t)m * MN + n;
        int msk = mask_u8 ? (int)mu8[idx] : mi32[idx];
        float dot = v[r];
        float pos = fmaxf(0.0f, 1.0f - dot) * 250.0f;
        float neg = fmaxf(0.0f, dot - 0.2f);
        lsum += msk ? pos : neg;
      }
    }
  }
#pragma unroll
  for (int off = 32; off > 0; off >>= 1) lsum += __shfl_xor(lsum, off);
  if (lane == 0) {
    size_t slot =
        (((size_t)bz * gridDim.y + bm) * gridDim.x + bn) * 4 + wave;
    part[slot] = lsum;                      // contention-free store
  }
}

// Sum 8192 partials -> out[0]. One block; overwrites out (no pre-zero needed).
__global__ __launch_bounds__(1024) void reduce_partials(
    const float* __restrict__ part, float* __restrict__ out) {
  float s = 0.0f;
#pragma unroll
  for (int i = 0; i < NPART / 1024; ++i) s += part[threadIdx.x + i * 1024];
#pragma unroll
  for (int off = 32; off > 0; off >>= 1) s += __shfl_xor(s, off);
  __shared__ float red[16];
  if ((threadIdx.x & 63) == 0) red[threadIdx.x >> 6] = s;
  __syncthreads();
  if (threadIdx.x == 0) {
    float t = 0.0f;
#pragma unroll
    for (int i = 0; i < 16; ++i) t += red[i];
    *out = t * TOTAL_INV;
  }
}

extern "C" void kernel_launch(void* const* d_in, const int* in_sizes, int n_in,
                              void* d_out, int out_size, void* d_ws, size_t ws_size,
                              hipStream_t stream) {
  const float* d0 = (const float*)d_in[0];
  const float* d1 = (const float*)d_in[1];
  const void* mask = d_in[2];
  float* out = (float*)d_out;

  unsigned short* Aw = (unsigned short*)d_ws;            // [B, M, D] bf16, 2 MB
  unsigned short* Bw = Aw + (size_t)BN * MN * DN;        // [B, M, D] bf16, 2 MB
  float* part = (float*)(Bw + (size_t)BN * MN * DN);     // 8192 f32, 32 KB

  dim3 g1(MN / 64, DN / 64, BN * 2), b1(256);
  transpose_cvt<<<g1, b1, 0, stream>>>(d0, d1, Aw, Bw);

  dim3 g2(MN / 128, MN / 128, BN), b2(256);
  gemm_loss<<<g2, b2, 0, stream>>>(Aw, Bw, mask, part);

  reduce_partials<<<1, 1024, 0, stream>>>(part, out);
}